// Round 12
// baseline (250.852 us; speedup 1.0000x reference)
//
#include <hip/hip_runtime.h>
#include <math.h>

#define B_ 2
#define C_ 1024
#define D_ 1024
#define H_ 16
#define DH_ 64
#define EPSF 1e-8f

typedef __bf16 bf16;
typedef __attribute__((ext_vector_type(4))) __bf16 bf16x4;
typedef __attribute__((ext_vector_type(8))) __bf16 bf16x8;
typedef __attribute__((ext_vector_type(4))) float f32x4;

__device__ inline f32x4 mfma16(bf16x8 a, bf16x8 b, f32x4 c) {
  return __builtin_amdgcn_mfma_f32_16x16x32_bf16(a, b, c, 0, 0, 0);
}

__device__ inline void async16(const bf16* g, bf16* l) {
  __builtin_amdgcn_global_load_lds((const __attribute__((address_space(1))) void*)g,
                                   (__attribute__((address_space(3))) void*)l, 16, 0, 0);
}

// theta for rope pair index i (reference uses (i-1)): 10000^(-2(i-1)/64)
__device__ inline float rope_theta(float i) {
  return exp2f(-13.287712379549449f * (2.0f * (i - 1.0f) * (1.0f / 64.0f)));
}

// Fragment-ordered staging (BK=64): LDS 16B-block index f = rg*128 + kkh*64 + lq*16 + lm
// holds global (row = rg*16+lm, col = kkh*32 + lq*8). MFMA fragment reads are then
// lane-linear consecutive b128 -> conflict-free (round-11 theory: BK=32 row-stride
// aliasing made fragment reads ~8-way conflicted).
#define STAGE(SRC, DST, ROWS, BASEROW, LDK)                                          \
  _Pragma("unroll") for (int p = 0; p < (ROWS) / 32; ++p) {                          \
    int lin = p * 256 + t;                                                           \
    int rg = lin >> 7, kkh = (lin >> 6) & 1, lq2 = (lin >> 4) & 3, lm2 = lin & 15;   \
    async16(SRC + (size_t)((BASEROW) + rg * 16 + lm2) * (LDK) + k0 + kkh * 32 +      \
                lq2 * 8,                                                             \
            DST + lin * 8);                                                          \
  }
// fragment elem offset for row-group rg, k-half kkh: (rg*128 + kkh*64 + lq*16 + lm)*8
#define FRAG(BUF, RG, KKH) (*(const bf16x8*)((BUF) + ((RG)*128 + (KKH)*64 + lq * 16 + lm) * 8))

// ---------------- fused: weight cvt (segs 0..6) + RMSNorm fp32->bf16 (blocks 7168+) ----------------
__global__ __launch_bounds__(256) void cvt_rms_kernel(const float* __restrict__ wqkv,
                                                      const float* __restrict__ wout,
                                                      const float* __restrict__ wf,
                                                      const float* __restrict__ www,
                                                      const float* __restrict__ wv,
                                                      bf16* __restrict__ wdst,
                                                      const float* __restrict__ x,
                                                      const float* __restrict__ rw,
                                                      const float* __restrict__ rb,
                                                      bf16* __restrict__ xout) {
  __shared__ float red[4];
  int t = threadIdx.x;
  if (blockIdx.x < 7 * 1024) {
    int seg = blockIdx.x >> 10;
    int local = (blockIdx.x & 1023) * 1024 + t * 4;
    const float* src = seg < 3 ? wqkv + (size_t)seg * (D_ * D_)
                     : seg == 3 ? wout : seg == 4 ? wf : seg == 5 ? www : wv;
    float4 v = *(const float4*)(src + local);
    bf16x4 o;
    o[0] = (bf16)v.x; o[1] = (bf16)v.y; o[2] = (bf16)v.z; o[3] = (bf16)v.w;
    *(bf16x4*)(wdst + (size_t)seg * (D_ * D_) + local) = o;
    return;
  }
  int row = blockIdx.x - 7 * 1024;
  int c = row & (C_ - 1);
  float4 xv = *(const float4*)(x + (size_t)row * D_ + t * 4);
  float ss = xv.x * xv.x + xv.y * xv.y + xv.z * xv.z + xv.w * xv.w;
#pragma unroll
  for (int m = 1; m < 64; m <<= 1) ss += __shfl_xor(ss, m, 64);
  if ((t & 63) == 0) red[t >> 6] = ss;
  __syncthreads();
  float tot = red[0] + red[1] + red[2] + red[3];
  float inv = rsqrtf(tot * (1.0f / D_) + EPSF);
  float4 wv4 = *(const float4*)(rw + (size_t)c * D_ + t * 4);
  float4 bv4 = *(const float4*)(rb + (size_t)c * D_ + t * 4);
  bf16x4 ov;
  ov[0] = (bf16)(wv4.x * (xv.x * inv) + bv4.x);
  ov[1] = (bf16)(wv4.y * (xv.y * inv) + bv4.y);
  ov[2] = (bf16)(wv4.z * (xv.z * inv) + bv4.z);
  ov[3] = (bf16)(wv4.w * (xv.w * inv) + bv4.w);
  *(bf16x4*)(xout + (size_t)row * D_ + t * 4) = ov;
}

// ---------------- RMSNorm (bf16 in, bf16 out) ----------------
__global__ __launch_bounds__(256) void rmsnorm_bf16_kernel(const bf16* __restrict__ x,
                                                           const float* __restrict__ w,
                                                           const float* __restrict__ b,
                                                           bf16* __restrict__ out) {
  int row = blockIdx.x;
  int c = row & (C_ - 1);
  int t = threadIdx.x;
  bf16x4 xv = *(const bf16x4*)(x + (size_t)row * D_ + t * 4);
  float f0 = (float)xv[0], f1 = (float)xv[1], f2 = (float)xv[2], f3 = (float)xv[3];
  float ss = f0 * f0 + f1 * f1 + f2 * f2 + f3 * f3;
#pragma unroll
  for (int m = 1; m < 64; m <<= 1) ss += __shfl_xor(ss, m, 64);
  __shared__ float red[4];
  if ((t & 63) == 0) red[t >> 6] = ss;
  __syncthreads();
  float tot = red[0] + red[1] + red[2] + red[3];
  float inv = rsqrtf(tot * (1.0f / D_) + EPSF);
  float4 wv = *(const float4*)(w + (size_t)c * D_ + t * 4);
  float4 bv = *(const float4*)(b + (size_t)c * D_ + t * 4);
  bf16x4 ov;
  ov[0] = (bf16)(wv.x * (f0 * inv) + bv.x);
  ov[1] = (bf16)(wv.y * (f1 * inv) + bv.y);
  ov[2] = (bf16)(wv.z * (f2 * inv) + bv.z);
  ov[3] = (bf16)(wv.w * (f3 * inv) + bv.w);
  *(bf16x4*)(out + (size_t)row * D_ + t * 4) = ov;
}

// ---------------- generic GEMM: fragment-ordered LDS, BK=64 ----------------
template <int BMt, int BNt>
__global__ __launch_bounds__(256) void gemm_lds(const bf16* __restrict__ A,
                                                const bf16* __restrict__ W,
                                                const float* __restrict__ bias,
                                                const bf16* __restrict__ R,
                                                bf16* __restrict__ Cout,
                                                int M, int N, int K) {
  constexpr int MT = BMt / 32;
  constexpr int NT = BNt / 32;
  __shared__ bf16 sa[BMt * 64];
  __shared__ bf16 sb[BNt * 64];
  int t = threadIdx.x, l = t & 63, w = t >> 6;
  int m0 = blockIdx.y * BMt;
  int n0 = blockIdx.x * BNt;
  int wm = (w >> 1) * (BMt / 2), wn = (w & 1) * (BNt / 2);
  int lm = l & 15, lq = l >> 4;
  int arg = wm >> 4, brg = wn >> 4;  // base row-groups for this wave
  f32x4 acc[MT][NT] = {};

  for (int k0 = 0; k0 < K; k0 += 64) {
    __syncthreads();
    STAGE(A, sa, BMt, m0, K)
    STAGE(W, sb, BNt, n0, K)
    __syncthreads();
#pragma unroll
    for (int kkh = 0; kkh < 2; ++kkh) {
      bf16x8 af[MT], bfr[NT];
#pragma unroll
      for (int mt = 0; mt < MT; ++mt) af[mt] = FRAG(sa, arg + mt, kkh);
#pragma unroll
      for (int nt = 0; nt < NT; ++nt) bfr[nt] = FRAG(sb, brg + nt, kkh);
#pragma unroll
      for (int mt = 0; mt < MT; ++mt)
#pragma unroll
        for (int nt = 0; nt < NT; ++nt)
          acc[mt][nt] = mfma16(af[mt], bfr[nt], acc[mt][nt]);
    }
  }
#pragma unroll
  for (int mt = 0; mt < MT; ++mt)
#pragma unroll
    for (int nt = 0; nt < NT; ++nt) {
      int col = n0 + wn + nt * 16 + lm;
      float bb = bias ? bias[col] : 0.0f;
#pragma unroll
      for (int r = 0; r < 4; ++r) {
        int row = m0 + wm + mt * 16 + lq * 4 + r;
        float v = acc[mt][nt][r] + bb;
        if (R) v += (float)R[(size_t)row * N + col];
        Cout[(size_t)row * N + col] = (bf16)v;
      }
    }
}

// ---------------- QKV GEMM <128,64> BK=64, fused V-transpose epilogue ----------------
__global__ __launch_bounds__(256) void gemm_qkv_kernel(const bf16* __restrict__ A,
                                                       const bf16* __restrict__ W,
                                                       bf16* __restrict__ qkv,
                                                       bf16* __restrict__ vt) {
  constexpr int BMt = 128, BNt = 64, MT = 4, NT = 2;
  const int N = 3 * D_, K = D_;
  __shared__ bf16 smem[BMt * 64 + BNt * 64];  // sa | sb ; tv aliases after K-loop
  bf16* sa = smem;
  bf16* sb = smem + BMt * 64;
  bf16* tv = smem;  // 64*136 = 8704 elems <= 12288
  int t = threadIdx.x, l = t & 63, w = t >> 6;
  int m0 = blockIdx.y * BMt;
  int n0 = blockIdx.x * BNt;
  int wm = (w >> 1) * 64, wn = (w & 1) * 32;
  int lm = l & 15, lq = l >> 4;
  int arg = wm >> 4, brg = wn >> 4;
  f32x4 acc[MT][NT] = {};

  for (int k0 = 0; k0 < K; k0 += 64) {
    __syncthreads();
    STAGE(A, sa, BMt, m0, K)
    STAGE(W, sb, BNt, n0, K)
    __syncthreads();
#pragma unroll
    for (int kkh = 0; kkh < 2; ++kkh) {
      bf16x8 af[MT], bfr[NT];
#pragma unroll
      for (int mt = 0; mt < MT; ++mt) af[mt] = FRAG(sa, arg + mt, kkh);
#pragma unroll
      for (int nt = 0; nt < NT; ++nt) bfr[nt] = FRAG(sb, brg + nt, kkh);
#pragma unroll
      for (int mt = 0; mt < MT; ++mt)
#pragma unroll
        for (int nt = 0; nt < NT; ++nt)
          acc[mt][nt] = mfma16(af[mt], bfr[nt], acc[mt][nt]);
    }
  }
  if (n0 < 2 * D_) {
    // Q/K: row-major into qkv
#pragma unroll
    for (int mt = 0; mt < MT; ++mt)
#pragma unroll
      for (int nt = 0; nt < NT; ++nt) {
        int col = n0 + wn + nt * 16 + lm;
#pragma unroll
        for (int r = 0; r < 4; ++r) {
          int row = m0 + wm + mt * 16 + lq * 4 + r;
          qkv[(size_t)row * N + col] = (bf16)acc[mt][nt][r];
        }
      }
  } else {
    // V: transpose via LDS (aliases sa/sb; all waves done reading after barrier)
    __syncthreads();
#pragma unroll
    for (int mt = 0; mt < MT; ++mt)
#pragma unroll
      for (int nt = 0; nt < NT; ++nt) {
        int dh = wn + nt * 16 + lm;
#pragma unroll
        for (int r = 0; r < 4; ++r)
          tv[dh * 136 + wm + mt * 16 + lq * 4 + r] = (bf16)acc[mt][nt][r];
      }
    __syncthreads();
    int h = (n0 - 2 * D_) >> 6;
    int bb = m0 >> 10;
    int mloc = m0 & 1023;
    size_t vbase = (size_t)((bb * H_ + h) * DH_) * C_;
#pragma unroll
    for (int p = 0; p < 4; ++p) {
      int lin = p * 256 + t;
      int dh = lin >> 4;
      int mm = (lin & 15) * 8;
      *(int4*)(vt + vbase + (size_t)dh * C_ + mloc + mm) = *(int4*)(tv + dh * 136 + mm);
    }
  }
}

// ---------------- Fused FFN tail: BK=64 fragment-ordered ----------------
__global__ __launch_bounds__(256) void gemm_ffn_kernel(const bf16* __restrict__ A,
                                                       const bf16* __restrict__ Ww,
                                                       const bf16* __restrict__ Wv,
                                                       const float* __restrict__ bw,
                                                       const float* __restrict__ bv,
                                                       const bf16* __restrict__ x3,
                                                       const float* __restrict__ beta_p,
                                                       float* __restrict__ out) {
  __shared__ bf16 sa[64 * 64];
  __shared__ bf16 sb1[64 * 64];
  __shared__ bf16 sb2[64 * 64];
  int t = threadIdx.x, l = t & 63, w = t >> 6;
  int m0 = blockIdx.y * 64, n0 = blockIdx.x * 64;
  int wm = (w >> 1) * 32, wn = (w & 1) * 32;
  int lm = l & 15, lq = l >> 4;
  int arg = wm >> 4, brg = wn >> 4;
  float beta = beta_p[0];
  f32x4 acc1[2][2] = {}, acc2[2][2] = {};

  for (int k0 = 0; k0 < D_; k0 += 64) {
    __syncthreads();
    STAGE(A, sa, 64, m0, D_)
    STAGE(Ww, sb1, 64, n0, D_)
    STAGE(Wv, sb2, 64, n0, D_)
    __syncthreads();
#pragma unroll
    for (int kkh = 0; kkh < 2; ++kkh) {
      bf16x8 af[2], b1f[2], b2f[2];
#pragma unroll
      for (int mt = 0; mt < 2; ++mt) af[mt] = FRAG(sa, arg + mt, kkh);
#pragma unroll
      for (int nt = 0; nt < 2; ++nt) {
        b1f[nt] = FRAG(sb1, brg + nt, kkh);
        b2f[nt] = FRAG(sb2, brg + nt, kkh);
      }
#pragma unroll
      for (int mt = 0; mt < 2; ++mt)
#pragma unroll
        for (int nt = 0; nt < 2; ++nt) {
          acc1[mt][nt] = mfma16(af[mt], b1f[nt], acc1[mt][nt]);
          acc2[mt][nt] = mfma16(af[mt], b2f[nt], acc2[mt][nt]);
        }
    }
  }
#pragma unroll
  for (int mt = 0; mt < 2; ++mt)
#pragma unroll
    for (int nt = 0; nt < 2; ++nt) {
      int col = n0 + wn + nt * 16 + lm;
      float bbw = bw[col], bbv = bv[col];
#pragma unroll
      for (int r = 0; r < 4; ++r) {
        int row = m0 + wm + mt * 16 + lq * 4 + r;
        float z = acc1[mt][nt][r] + bbw;
        float g = acc2[mt][nt][r] + bbv;
        float sw = z / (1.0f + __expf(-beta * z));
        out[(size_t)row * D_ + col] = (float)x3[(size_t)row * D_ + col] + sw * g;
      }
    }
}

// ---------------- Fused attention v4 (unchanged from round 11) ----------------
__global__ __launch_bounds__(256) void attn_kernel(const bf16* __restrict__ qkv,
                                                   const bf16* __restrict__ vt,
                                                   float* __restrict__ yp,
                                                   float* __restrict__ dp) {
  __shared__ bf16 sk[64 * 72];
  __shared__ bf16 skr[64 * 72];
  __shared__ bf16 sv[64 * 72];
  __shared__ bf16 pl[4][16 * 72];
  int t = threadIdx.x, l = t & 63, w = t >> 6;
  int blk = blockIdx.x;  // 1024
  int it = blk >> 6;
  int r6 = blk & 63;
  int b = r6 >> 5;
  int h = (r6 >> 1) & 15;
  int half = r6 & 1;
  int i_base = it * 64 + w * 16;
  int lm = l & 15, lq = l >> 4;
  const float scale = 0.125f;
  int jf = half << 9;

  size_t hq = (size_t)h * DH_;
  size_t qrow = (size_t)(b * C_ + i_base + lm) * (3 * D_) + hq;
  bf16x8 qp[2], qrf[2];
  float cq = (float)(i_base + lm);
#pragma unroll
  for (int kk = 0; kk < 2; ++kk) {
    qp[kk] = *(const bf16x8*)(qkv + qrow + kk * 32 + lq * 8);
#pragma unroll
    for (int j = 0; j < 4; ++j) {
      float ip = (float)(kk * 16 + lq * 4 + j);
      float ang = cq * rope_theta(ip);
      float sv_, cv_;
      __sincosf(ang, &sv_, &cv_);
      float qe = (float)qp[kk][2 * j], qo = (float)qp[kk][2 * j + 1];
      qrf[kk][2 * j] = (bf16)(qe * cv_ + qo * sv_);
      qrf[kk][2 * j + 1] = (bf16)(qo * cv_ - qe * sv_);
    }
  }

  float den[4] = {0.f, 0.f, 0.f, 0.f};
  f32x4 yacc[4] = {};
  int i_max = i_base + 15;
  size_t kbase = (size_t)(b * C_) * (3 * D_) + D_ + hq;
  size_t vtbase = (size_t)((b * H_ + h) * DH_) * C_;
  int sr = t >> 3;
  int sc = (t & 7) * 8;
  float th0 = rope_theta((float)((sc >> 1) + 0));
  float th1 = rope_theta((float)((sc >> 1) + 1));
  float th2 = rope_theta((float)((sc >> 1) + 2));
  float th3 = rope_theta((float)((sc >> 1) + 3));

  float cA0, sA0, cA1, sA1, cA2, sA2, cA3, sA3;
  float cB0, sB0, cB1, sB1, cB2, sB2, cB3, sB3;
  float C0, S0, C1, S1, C2, S2, C3, S3;
#define INITP(P)                       \
  {                                    \
    float a;                           \
    a = (float)(jf + sr) * th##P;      \
    __sincosf(a, &sA##P, &cA##P);      \
    a = (float)(jf + 32 + sr) * th##P; \
    __sincosf(a, &sB##P, &cB##P);      \
    a = 64.0f * th##P;                 \
    __sincosf(a, &S##P, &C##P);        \
  }
  INITP(0) INITP(1) INITP(2) INITP(3)
#undef INITP

  int4 pk0, pk1, pv0, pv1;
#define FETCH_TILE(J0)                                                          \
  pk0 = *(const int4*)(qkv + kbase + (size_t)((J0) + sr) * (3 * D_) + sc);      \
  pk1 = *(const int4*)(qkv + kbase + (size_t)((J0) + 32 + sr) * (3 * D_) + sc); \
  pv0 = *(const int4*)(vt + vtbase + (size_t)sr * C_ + (J0) + sc);              \
  pv1 = *(const int4*)(vt + vtbase + (size_t)(32 + sr) * C_ + (J0) + sc);

  FETCH_TILE(jf)

  for (int j0 = jf; j0 < jf + 512; j0 += 64) {
    __syncthreads();
    *(int4*)(sk + sr * 72 + sc) = pk0;
    *(int4*)(sk + (32 + sr) * 72 + sc) = pk1;
    *(int4*)(sv + sr * 72 + sc) = pv0;
    *(int4*)(sv + (32 + sr) * 72 + sc) = pv1;
    {
      bf16x8 k0 = *(bf16x8*)&pk0, k1 = *(bf16x8*)&pk1;
      bf16x8 r0, r1;
#define ROT2(KV, RV, CC, SS, J)                           \
  {                                                       \
    float e = (float)KV[2 * J], o = (float)KV[2 * J + 1]; \
    RV[2 * J] = (bf16)(e * CC + o * SS);                  \
    RV[2 * J + 1] = (bf16)(o * CC - e * SS);              \
  }
      ROT2(k0, r0, cA0, sA0, 0) ROT2(k0, r0, cA1, sA1, 1)
      ROT2(k0, r0, cA2, sA2, 2) ROT2(k0, r0, cA3, sA3, 3)
      ROT2(k1, r1, cB0, sB0, 0) ROT2(k1, r1, cB1, sB1, 1)
      ROT2(k1, r1, cB2, sB2, 2) ROT2(k1, r1, cB3, sB3, 3)
#undef ROT2
#define STEP(CX, SX, P)               \
  {                                   \
    float nc = CX * C##P - SX * S##P; \
    SX = SX * C##P + CX * S##P;       \
    CX = nc;                          \
  }
      STEP(cA0, sA0, 0) STEP(cA1, sA1, 1) STEP(cA2, sA2, 2) STEP(cA3, sA3, 3)
      STEP(cB0, sB0, 0) STEP(cB1, sB1, 1) STEP(cB2, sB2, 2) STEP(cB3, sB3, 3)
#undef STEP
      *(int4*)(skr + sr * 72 + sc) = *(int4*)&r0;
      *(int4*)(skr + (32 + sr) * 72 + sc) = *(int4*)&r1;
    }
    __syncthreads();
    if (j0 + 64 < jf + 512) {
      FETCH_TILE(j0 + 64)
    }
#pragma unroll
    for (int js = 0; js < 64; js += 16) {
      bf16x8 kf0 = *(const bf16x8*)(sk + (js + lm) * 72 + lq * 8);
      bf16x8 kf1 = *(const bf16x8*)(sk + (js + lm) * 72 + 32 + lq * 8);
      f32x4 s = {0.f, 0.f, 0.f, 0.f};
      s = mfma16(qp[0], kf0, s);
      s = mfma16(qp[1], kf1, s);
#pragma unroll
      for (int r = 0; r < 4; ++r) den[r] += __expf(s[r] * scale);
    }
    if (j0 <= i_max) {
#pragma unroll
      for (int js = 0; js < 64; js += 16) {
        bf16x8 kf0 = *(const bf16x8*)(skr + (js + lm) * 72 + lq * 8);
        bf16x8 kf1 = *(const bf16x8*)(skr + (js + lm) * 72 + 32 + lq * 8);
        f32x4 s = {0.f, 0.f, 0.f, 0.f};
        s = mfma16(qrf[0], kf0, s);
        s = mfma16(qrf[1], kf1, s);
#pragma unroll
        for (int r = 0; r < 4; ++r) {
          int jg = j0 + js + lm;
          int ig = i_base + lq * 4 + r;
          float p = (jg <= ig) ? __expf(s[r] * scale) : 0.0f;
          pl[w][(lq * 4 + r) * 72 + js + lm] = (bf16)p;
        }
      }
      __builtin_amdgcn_wave_barrier();
      bf16x8 pf0 = *(const bf16x8*)(pl[w] + lm * 72 + lq * 8);
      bf16x8 pf1 = *(const bf16x8*)(pl[w] + lm * 72 + 32 + lq * 8);
#pragma unroll
      for (int tt = 0; tt < 4; ++tt) {
        bf16x8 vf0 = *(const bf16x8*)(sv + (tt * 16 + lm) * 72 + lq * 8);
        bf16x8 vf1 = *(const bf16x8*)(sv + (tt * 16 + lm) * 72 + 32 + lq * 8);
        yacc[tt] = mfma16(pf0, vf0, mfma16(pf1, vf1, yacc[tt]));
      }
      __builtin_amdgcn_wave_barrier();
    }
  }
#undef FETCH_TILE
#pragma unroll
  for (int r = 0; r < 4; ++r) {
    float d = den[r];
    d += __shfl_xor(d, 1, 64);
    d += __shfl_xor(d, 2, 64);
    d += __shfl_xor(d, 4, 64);
    d += __shfl_xor(d, 8, 64);
    if (lm == 0) dp[(size_t)blk * 64 + w * 16 + lq * 4 + r] = d;
  }
  size_t yb = (size_t)blk * 4096;
#pragma unroll
  for (int tt = 0; tt < 4; ++tt)
#pragma unroll
    for (int r = 0; r < 4; ++r)
      yp[yb + (size_t)(w * 16 + lq * 4 + r) * 64 + tt * 16 + lm] = yacc[tt][r];
}

// ---------------- combine halves: y = (y0+y1)/(d0+d1) ----------------
__global__ __launch_bounds__(256) void combine_kernel(const float* __restrict__ yp,
                                                      const float* __restrict__ dp,
                                                      bf16* __restrict__ y) {
  int cb = blockIdx.x;  // 512
  int it = cb >> 5;
  int b = (cb >> 4) & 1;
  int h = cb & 15;
  int t = threadIdx.x;
  int row = t >> 2;
  int cg = (t & 3) * 16;
  size_t p0 = (size_t)(cb * 2) * 4096 + (size_t)row * 64 + cg;
  size_t p1 = p0 + 4096;
  float inv = 1.0f / (dp[(size_t)(cb * 2) * 64 + row] + dp[(size_t)(cb * 2 + 1) * 64 + row]);
  bf16x8 o0, o1;
#pragma unroll
  for (int c = 0; c < 8; ++c) o0[c] = (bf16)((yp[p0 + c] + yp[p1 + c]) * inv);
#pragma unroll
  for (int c = 0; c < 8; ++c) o1[c] = (bf16)((yp[p0 + 8 + c] + yp[p1 + 8 + c]) * inv);
  size_t ob = (size_t)(b * C_ + it * 64 + row) * D_ + h * DH_ + cg;
  *(bf16x8*)(y + ob) = o0;
  *(bf16x8*)(y + ob + 8) = o1;
}

extern "C" void kernel_launch(void* const* d_in, const int* in_sizes, int n_in,
                              void* d_out, int out_size, void* d_ws, size_t ws_size,
                              hipStream_t stream) {
  const float* x = (const float*)d_in[0];
  const float* rms_w = (const float*)d_in[1];
  const float* rms_b = (const float*)d_in[2];
  const float* Wqkv = (const float*)d_in[3];
  const float* Wout = (const float*)d_in[4];
  const float* bout = (const float*)d_in[5];
  const float* Wf = (const float*)d_in[6];
  const float* bfp = (const float*)d_in[7];
  const float* Ww = (const float*)d_in[8];
  const float* bw = (const float*)d_in[9];
  const float* Wv = (const float*)d_in[10];
  const float* bv = (const float*)d_in[11];
  const float* beta = (const float*)d_in[12];
  float* out = (float*)d_out;

  bf16* ws = (bf16*)d_ws;
  const size_t DD = (size_t)D_ * D_;
  const size_t MC = (size_t)B_ * C_;
  bf16* wb = ws;                       // 7DD: Wqkv(3), Wout, Wf, Ww, Wv
  bf16* x1 = ws + 7 * DD;
  bf16* qkv = ws + 9 * DD;
  bf16* vt = ws + 15 * DD;
  bf16* x2 = ws + 17 * DD;
  bf16* x3 = ws + 19 * DD;
  bf16* hbuf = ws + 21 * DD;
  float* yp = (float*)(ws + 24 * DD);  // 16 MB
  float* dp = yp + (size_t)1024 * 4096;
  bf16* y = (bf16*)d_out;  // bf16 y inside fp32 d_out; consumed before final write

  cvt_rms_kernel<<<7 * 1024 + MC, 256, 0, stream>>>(Wqkv, Wout, Wf, Ww, Wv, wb, x, rms_w,
                                                    rms_b, x1);
  gemm_qkv_kernel<<<dim3(3 * D_ / 64, MC / 128), 256, 0, stream>>>(x1, wb, qkv, vt);
  attn_kernel<<<B_ * H_ * 16 * 2, 256, 0, stream>>>(qkv, vt, yp, dp);
  combine_kernel<<<B_ * H_ * 16, 256, 0, stream>>>(yp, dp, y);
  gemm_lds<64, 64><<<dim3(D_ / 64, MC / 64), 256, 0, stream>>>(
      y, wb + 3 * DD, bout, x1, x2, MC, D_, D_);
  rmsnorm_bf16_kernel<<<MC, 256, 0, stream>>>(x2, rms_w, rms_b, x3);
  gemm_lds<64, 64><<<dim3(D_ / 64, MC / 64), 256, 0, stream>>>(
      x3, wb + 4 * DD, bfp, nullptr, hbuf, MC, D_, D_);
  gemm_ffn_kernel<<<dim3(D_ / 64, MC / 64), 256, 0, stream>>>(
      hbuf, wb + 5 * DD, wb + 6 * DD, bw, bv, x3, beta, out);
}

// Round 13
// 228.230 us; speedup vs baseline: 1.0991x; 1.0991x over previous
//
#include <hip/hip_runtime.h>
#include <math.h>

#define B_ 2
#define C_ 1024
#define D_ 1024
#define H_ 16
#define DH_ 64
#define EPSF 1e-8f
#define BK 32

typedef __bf16 bf16;
typedef __attribute__((ext_vector_type(4))) __bf16 bf16x4;
typedef __attribute__((ext_vector_type(8))) __bf16 bf16x8;
typedef __attribute__((ext_vector_type(4))) float f32x4;

__device__ inline f32x4 mfma16(bf16x8 a, bf16x8 b, f32x4 c) {
  return __builtin_amdgcn_mfma_f32_16x16x32_bf16(a, b, c, 0, 0, 0);
}

__device__ inline void async16(const bf16* g, bf16* l) {
  __builtin_amdgcn_global_load_lds((const __attribute__((address_space(1))) void*)g,
                                   (__attribute__((address_space(3))) void*)l, 16, 0, 0);
}

// theta for rope pair index i (reference uses (i-1)): 10000^(-2(i-1)/64)
__device__ inline float rope_theta(float i) {
  return exp2f(-13.287712379549449f * (2.0f * (i - 1.0f) * (1.0f / 64.0f)));
}

// ---------------- fused: weight cvt (segs 0..6) + RMSNorm fp32->bf16 (blocks 7168+) ----------------
__global__ __launch_bounds__(256) void cvt_rms_kernel(const float* __restrict__ wqkv,
                                                      const float* __restrict__ wout,
                                                      const float* __restrict__ wf,
                                                      const float* __restrict__ www,
                                                      const float* __restrict__ wv,
                                                      bf16* __restrict__ wdst,
                                                      const float* __restrict__ x,
                                                      const float* __restrict__ rw,
                                                      const float* __restrict__ rb,
                                                      bf16* __restrict__ xout) {
  __shared__ float red[4];
  int t = threadIdx.x;
  if (blockIdx.x < 7 * 1024) {
    int seg = blockIdx.x >> 10;
    int local = (blockIdx.x & 1023) * 1024 + t * 4;
    const float* src = seg < 3 ? wqkv + (size_t)seg * (D_ * D_)
                     : seg == 3 ? wout : seg == 4 ? wf : seg == 5 ? www : wv;
    float4 v = *(const float4*)(src + local);
    bf16x4 o;
    o[0] = (bf16)v.x; o[1] = (bf16)v.y; o[2] = (bf16)v.z; o[3] = (bf16)v.w;
    *(bf16x4*)(wdst + (size_t)seg * (D_ * D_) + local) = o;
    return;
  }
  int row = blockIdx.x - 7 * 1024;
  int c = row & (C_ - 1);
  float4 xv = *(const float4*)(x + (size_t)row * D_ + t * 4);
  float ss = xv.x * xv.x + xv.y * xv.y + xv.z * xv.z + xv.w * xv.w;
#pragma unroll
  for (int m = 1; m < 64; m <<= 1) ss += __shfl_xor(ss, m, 64);
  if ((t & 63) == 0) red[t >> 6] = ss;
  __syncthreads();
  float tot = red[0] + red[1] + red[2] + red[3];
  float inv = rsqrtf(tot * (1.0f / D_) + EPSF);
  float4 wv4 = *(const float4*)(rw + (size_t)c * D_ + t * 4);
  float4 bv4 = *(const float4*)(rb + (size_t)c * D_ + t * 4);
  bf16x4 ov;
  ov[0] = (bf16)(wv4.x * (xv.x * inv) + bv4.x);
  ov[1] = (bf16)(wv4.y * (xv.y * inv) + bv4.y);
  ov[2] = (bf16)(wv4.z * (xv.z * inv) + bv4.z);
  ov[3] = (bf16)(wv4.w * (xv.w * inv) + bv4.w);
  *(bf16x4*)(xout + (size_t)row * D_ + t * 4) = ov;
}

// ---------------- RMSNorm (bf16 in, bf16 out) ----------------
__global__ __launch_bounds__(256) void rmsnorm_bf16_kernel(const bf16* __restrict__ x,
                                                           const float* __restrict__ w,
                                                           const float* __restrict__ b,
                                                           bf16* __restrict__ out) {
  int row = blockIdx.x;
  int c = row & (C_ - 1);
  int t = threadIdx.x;
  bf16x4 xv = *(const bf16x4*)(x + (size_t)row * D_ + t * 4);
  float f0 = (float)xv[0], f1 = (float)xv[1], f2 = (float)xv[2], f3 = (float)xv[3];
  float ss = f0 * f0 + f1 * f1 + f2 * f2 + f3 * f3;
#pragma unroll
  for (int m = 1; m < 64; m <<= 1) ss += __shfl_xor(ss, m, 64);
  __shared__ float red[4];
  if ((t & 63) == 0) red[t >> 6] = ss;
  __syncthreads();
  float tot = red[0] + red[1] + red[2] + red[3];
  float inv = rsqrtf(tot * (1.0f / D_) + EPSF);
  float4 wv = *(const float4*)(w + (size_t)c * D_ + t * 4);
  float4 bv = *(const float4*)(b + (size_t)c * D_ + t * 4);
  bf16x4 ov;
  ov[0] = (bf16)(wv.x * (f0 * inv) + bv.x);
  ov[1] = (bf16)(wv.y * (f1 * inv) + bv.y);
  ov[2] = (bf16)(wv.z * (f2 * inv) + bv.z);
  ov[3] = (bf16)(wv.w * (f3 * inv) + bv.w);
  *(bf16x4*)(out + (size_t)row * D_ + t * 4) = ov;
}

// ---------------- generic GEMM (round-11 m97 structure, BK=32) ----------------
// BMt=32 supported: A staged by first 128 threads (waves 0,1 — wave-complete, contract-safe).
template <int BMt, int BNt>
__global__ __launch_bounds__(256) void gemm_lds(const bf16* __restrict__ A,
                                                const bf16* __restrict__ W,
                                                const float* __restrict__ bias,
                                                const bf16* __restrict__ R,
                                                bf16* __restrict__ Cout,
                                                int M, int N, int K) {
  constexpr int MT = BMt / 32;
  constexpr int NT = BNt / 32;
  __shared__ bf16 sa[BMt * BK];
  __shared__ bf16 sb[BNt * BK];
  int t = threadIdx.x, l = t & 63, w = t >> 6;
  int m0 = blockIdx.y * BMt;
  int n0 = blockIdx.x * BNt;
  int wm = (w >> 1) * (BMt / 2), wn = (w & 1) * (BNt / 2);
  int lm = l & 15, lq = l >> 4;
  f32x4 acc[MT][NT] = {};

  for (int k0 = 0; k0 < K; k0 += BK) {
    __syncthreads();
    if constexpr (BMt >= 64) {
#pragma unroll
      for (int p = 0; p < BMt / 64; ++p) {
        int lin = p * 256 + t;
        async16(A + (size_t)(m0 + (lin >> 2)) * K + k0 + (lin & 3) * 8, sa + lin * 8);
      }
    } else {
      if (t < BMt * 4)
        async16(A + (size_t)(m0 + (t >> 2)) * K + k0 + (t & 3) * 8, sa + t * 8);
    }
#pragma unroll
    for (int p = 0; p < BNt / 64; ++p) {
      int lin = p * 256 + t;
      async16(W + (size_t)(n0 + (lin >> 2)) * K + k0 + (lin & 3) * 8, sb + lin * 8);
    }
    __syncthreads();
    bf16x8 af[MT], bfr[NT];
#pragma unroll
    for (int mt = 0; mt < MT; ++mt)
      af[mt] = *(const bf16x8*)(sa + (wm + mt * 16 + lm) * BK + lq * 8);
#pragma unroll
    for (int nt = 0; nt < NT; ++nt)
      bfr[nt] = *(const bf16x8*)(sb + (wn + nt * 16 + lm) * BK + lq * 8);
#pragma unroll
    for (int mt = 0; mt < MT; ++mt)
#pragma unroll
      for (int nt = 0; nt < NT; ++nt)
        acc[mt][nt] = mfma16(af[mt], bfr[nt], acc[mt][nt]);
  }
#pragma unroll
  for (int mt = 0; mt < MT; ++mt)
#pragma unroll
    for (int nt = 0; nt < NT; ++nt) {
      int col = n0 + wn + nt * 16 + lm;
      float bb = bias ? bias[col] : 0.0f;
#pragma unroll
      for (int r = 0; r < 4; ++r) {
        int row = m0 + wm + mt * 16 + lq * 4 + r;
        float v = acc[mt][nt][r] + bb;
        if (R) v += (float)R[(size_t)row * N + col];
        Cout[(size_t)row * N + col] = (bf16)v;
      }
    }
}

// ---------------- QKV GEMM <128,64> BK=32 with fused V-transpose epilogue (round-11) ----------------
__global__ __launch_bounds__(256) void gemm_qkv_kernel(const bf16* __restrict__ A,
                                                       const bf16* __restrict__ W,
                                                       bf16* __restrict__ qkv,
                                                       bf16* __restrict__ vt) {
  constexpr int BMt = 128, BNt = 64, MT = 4, NT = 2;
  const int N = 3 * D_, K = D_;
  __shared__ bf16 sa[BMt * BK];
  __shared__ bf16 sb[BNt * BK];
  __shared__ bf16 tv[64 * 136];  // V transpose tile [dh][m]
  int t = threadIdx.x, l = t & 63, w = t >> 6;
  int m0 = blockIdx.y * BMt;
  int n0 = blockIdx.x * BNt;
  int wm = (w >> 1) * 64, wn = (w & 1) * 32;
  int lm = l & 15, lq = l >> 4;
  f32x4 acc[MT][NT] = {};

  for (int k0 = 0; k0 < K; k0 += BK) {
    __syncthreads();
#pragma unroll
    for (int p = 0; p < 2; ++p) {
      int lin = p * 256 + t;
      async16(A + (size_t)(m0 + (lin >> 2)) * K + k0 + (lin & 3) * 8, sa + lin * 8);
    }
    async16(W + (size_t)(n0 + (t >> 2)) * K + k0 + (t & 3) * 8, sb + t * 8);
    __syncthreads();
    bf16x8 af[MT], bfr[NT];
#pragma unroll
    for (int mt = 0; mt < MT; ++mt)
      af[mt] = *(const bf16x8*)(sa + (wm + mt * 16 + lm) * BK + lq * 8);
#pragma unroll
    for (int nt = 0; nt < NT; ++nt)
      bfr[nt] = *(const bf16x8*)(sb + (wn + nt * 16 + lm) * BK + lq * 8);
#pragma unroll
    for (int mt = 0; mt < MT; ++mt)
#pragma unroll
      for (int nt = 0; nt < NT; ++nt)
        acc[mt][nt] = mfma16(af[mt], bfr[nt], acc[mt][nt]);
  }
  if (n0 < 2 * D_) {
#pragma unroll
    for (int mt = 0; mt < MT; ++mt)
#pragma unroll
      for (int nt = 0; nt < NT; ++nt) {
        int col = n0 + wn + nt * 16 + lm;
#pragma unroll
        for (int r = 0; r < 4; ++r) {
          int row = m0 + wm + mt * 16 + lq * 4 + r;
          qkv[(size_t)row * N + col] = (bf16)acc[mt][nt][r];
        }
      }
  } else {
#pragma unroll
    for (int mt = 0; mt < MT; ++mt)
#pragma unroll
      for (int nt = 0; nt < NT; ++nt) {
        int dh = wn + nt * 16 + lm;
#pragma unroll
        for (int r = 0; r < 4; ++r)
          tv[dh * 136 + wm + mt * 16 + lq * 4 + r] = (bf16)acc[mt][nt][r];
      }
    __syncthreads();
    int h = (n0 - 2 * D_) >> 6;
    int bb = m0 >> 10;
    int mloc = m0 & 1023;
    size_t vbase = (size_t)((bb * H_ + h) * DH_) * C_;
#pragma unroll
    for (int p = 0; p < 4; ++p) {
      int lin = p * 256 + t;
      int dh = lin >> 4;
      int mm = (lin & 15) * 8;
      *(int4*)(vt + vbase + (size_t)dh * C_ + mloc + mm) = *(int4*)(tv + dh * 136 + mm);
    }
  }
}

// ---------------- Fused FFN tail (round-11, BK=32) ----------------
__global__ __launch_bounds__(256) void gemm_ffn_kernel(const bf16* __restrict__ A,
                                                       const bf16* __restrict__ Ww,
                                                       const bf16* __restrict__ Wv,
                                                       const float* __restrict__ bw,
                                                       const float* __restrict__ bv,
                                                       const bf16* __restrict__ x3,
                                                       const float* __restrict__ beta_p,
                                                       float* __restrict__ out) {
  __shared__ bf16 sa[64 * BK];
  __shared__ bf16 sb1[64 * BK];
  __shared__ bf16 sb2[64 * BK];
  int t = threadIdx.x, l = t & 63, w = t >> 6;
  int m0 = blockIdx.y * 64, n0 = blockIdx.x * 64;
  int wm = (w >> 1) * 32, wn = (w & 1) * 32;
  int lm = l & 15, lq = l >> 4;
  float beta = beta_p[0];
  f32x4 acc1[2][2] = {}, acc2[2][2] = {};

  for (int k0 = 0; k0 < D_; k0 += BK) {
    __syncthreads();
    async16(A + (size_t)(m0 + (t >> 2)) * D_ + k0 + (t & 3) * 8, sa + t * 8);
    async16(Ww + (size_t)(n0 + (t >> 2)) * D_ + k0 + (t & 3) * 8, sb1 + t * 8);
    async16(Wv + (size_t)(n0 + (t >> 2)) * D_ + k0 + (t & 3) * 8, sb2 + t * 8);
    __syncthreads();
    bf16x8 af[2], b1f[2], b2f[2];
#pragma unroll
    for (int mt = 0; mt < 2; ++mt)
      af[mt] = *(const bf16x8*)(sa + (wm + mt * 16 + lm) * BK + lq * 8);
#pragma unroll
    for (int nt = 0; nt < 2; ++nt) {
      b1f[nt] = *(const bf16x8*)(sb1 + (wn + nt * 16 + lm) * BK + lq * 8);
      b2f[nt] = *(const bf16x8*)(sb2 + (wn + nt * 16 + lm) * BK + lq * 8);
    }
#pragma unroll
    for (int mt = 0; mt < 2; ++mt)
#pragma unroll
      for (int nt = 0; nt < 2; ++nt) {
        acc1[mt][nt] = mfma16(af[mt], b1f[nt], acc1[mt][nt]);
        acc2[mt][nt] = mfma16(af[mt], b2f[nt], acc2[mt][nt]);
      }
  }
#pragma unroll
  for (int mt = 0; mt < 2; ++mt)
#pragma unroll
    for (int nt = 0; nt < 2; ++nt) {
      int col = n0 + wn + nt * 16 + lm;
      float bbw = bw[col], bbv = bv[col];
#pragma unroll
      for (int r = 0; r < 4; ++r) {
        int row = m0 + wm + mt * 16 + lq * 4 + r;
        float z = acc1[mt][nt][r] + bbw;
        float g = acc2[mt][nt][r] + bbv;
        float sw = z / (1.0f + __expf(-beta * z));
        out[(size_t)row * D_ + col] = (float)x3[(size_t)row * D_ + col] + sw * g;
      }
    }
}

// ---------------- Fused attention v4 (round-11, unchanged) ----------------
__global__ __launch_bounds__(256) void attn_kernel(const bf16* __restrict__ qkv,
                                                   const bf16* __restrict__ vt,
                                                   float* __restrict__ yp,
                                                   float* __restrict__ dp) {
  __shared__ bf16 sk[64 * 72];
  __shared__ bf16 skr[64 * 72];
  __shared__ bf16 sv[64 * 72];
  __shared__ bf16 pl[4][16 * 72];
  int t = threadIdx.x, l = t & 63, w = t >> 6;
  int blk = blockIdx.x;  // 1024
  int it = blk >> 6;
  int r6 = blk & 63;
  int b = r6 >> 5;
  int h = (r6 >> 1) & 15;
  int half = r6 & 1;
  int i_base = it * 64 + w * 16;
  int lm = l & 15, lq = l >> 4;
  const float scale = 0.125f;
  int jf = half << 9;

  size_t hq = (size_t)h * DH_;
  size_t qrow = (size_t)(b * C_ + i_base + lm) * (3 * D_) + hq;
  bf16x8 qp[2], qrf[2];
  float cq = (float)(i_base + lm);
#pragma unroll
  for (int kk = 0; kk < 2; ++kk) {
    qp[kk] = *(const bf16x8*)(qkv + qrow + kk * 32 + lq * 8);
#pragma unroll
    for (int j = 0; j < 4; ++j) {
      float ip = (float)(kk * 16 + lq * 4 + j);
      float ang = cq * rope_theta(ip);
      float sv_, cv_;
      __sincosf(ang, &sv_, &cv_);
      float qe = (float)qp[kk][2 * j], qo = (float)qp[kk][2 * j + 1];
      qrf[kk][2 * j] = (bf16)(qe * cv_ + qo * sv_);
      qrf[kk][2 * j + 1] = (bf16)(qo * cv_ - qe * sv_);
    }
  }

  float den[4] = {0.f, 0.f, 0.f, 0.f};
  f32x4 yacc[4] = {};
  int i_max = i_base + 15;
  size_t kbase = (size_t)(b * C_) * (3 * D_) + D_ + hq;
  size_t vtbase = (size_t)((b * H_ + h) * DH_) * C_;
  int sr = t >> 3;
  int sc = (t & 7) * 8;
  float th0 = rope_theta((float)((sc >> 1) + 0));
  float th1 = rope_theta((float)((sc >> 1) + 1));
  float th2 = rope_theta((float)((sc >> 1) + 2));
  float th3 = rope_theta((float)((sc >> 1) + 3));

  float cA0, sA0, cA1, sA1, cA2, sA2, cA3, sA3;
  float cB0, sB0, cB1, sB1, cB2, sB2, cB3, sB3;
  float C0, S0, C1, S1, C2, S2, C3, S3;
#define INITP(P)                       \
  {                                    \
    float a;                           \
    a = (float)(jf + sr) * th##P;      \
    __sincosf(a, &sA##P, &cA##P);      \
    a = (float)(jf + 32 + sr) * th##P; \
    __sincosf(a, &sB##P, &cB##P);      \
    a = 64.0f * th##P;                 \
    __sincosf(a, &S##P, &C##P);        \
  }
  INITP(0) INITP(1) INITP(2) INITP(3)
#undef INITP

  int4 pk0, pk1, pv0, pv1;
#define FETCH_TILE(J0)                                                          \
  pk0 = *(const int4*)(qkv + kbase + (size_t)((J0) + sr) * (3 * D_) + sc);      \
  pk1 = *(const int4*)(qkv + kbase + (size_t)((J0) + 32 + sr) * (3 * D_) + sc); \
  pv0 = *(const int4*)(vt + vtbase + (size_t)sr * C_ + (J0) + sc);              \
  pv1 = *(const int4*)(vt + vtbase + (size_t)(32 + sr) * C_ + (J0) + sc);

  FETCH_TILE(jf)

  for (int j0 = jf; j0 < jf + 512; j0 += 64) {
    __syncthreads();
    *(int4*)(sk + sr * 72 + sc) = pk0;
    *(int4*)(sk + (32 + sr) * 72 + sc) = pk1;
    *(int4*)(sv + sr * 72 + sc) = pv0;
    *(int4*)(sv + (32 + sr) * 72 + sc) = pv1;
    {
      bf16x8 k0 = *(bf16x8*)&pk0, k1 = *(bf16x8*)&pk1;
      bf16x8 r0, r1;
#define ROT2(KV, RV, CC, SS, J)                           \
  {                                                       \
    float e = (float)KV[2 * J], o = (float)KV[2 * J + 1]; \
    RV[2 * J] = (bf16)(e * CC + o * SS);                  \
    RV[2 * J + 1] = (bf16)(o * CC - e * SS);              \
  }
      ROT2(k0, r0, cA0, sA0, 0) ROT2(k0, r0, cA1, sA1, 1)
      ROT2(k0, r0, cA2, sA2, 2) ROT2(k0, r0, cA3, sA3, 3)
      ROT2(k1, r1, cB0, sB0, 0) ROT2(k1, r1, cB1, sB1, 1)
      ROT2(k1, r1, cB2, sB2, 2) ROT2(k1, r1, cB3, sB3, 3)
#undef ROT2
#define STEP(CX, SX, P)               \
  {                                   \
    float nc = CX * C##P - SX * S##P; \
    SX = SX * C##P + CX * S##P;       \
    CX = nc;                          \
  }
      STEP(cA0, sA0, 0) STEP(cA1, sA1, 1) STEP(cA2, sA2, 2) STEP(cA3, sA3, 3)
      STEP(cB0, sB0, 0) STEP(cB1, sB1, 1) STEP(cB2, sB2, 2) STEP(cB3, sB3, 3)
#undef STEP
      *(int4*)(skr + sr * 72 + sc) = *(int4*)&r0;
      *(int4*)(skr + (32 + sr) * 72 + sc) = *(int4*)&r1;
    }
    __syncthreads();
    if (j0 + 64 < jf + 512) {
      FETCH_TILE(j0 + 64)
    }
#pragma unroll
    for (int js = 0; js < 64; js += 16) {
      bf16x8 kf0 = *(const bf16x8*)(sk + (js + lm) * 72 + lq * 8);
      bf16x8 kf1 = *(const bf16x8*)(sk + (js + lm) * 72 + 32 + lq * 8);
      f32x4 s = {0.f, 0.f, 0.f, 0.f};
      s = mfma16(qp[0], kf0, s);
      s = mfma16(qp[1], kf1, s);
#pragma unroll
      for (int r = 0; r < 4; ++r) den[r] += __expf(s[r] * scale);
    }
    if (j0 <= i_max) {
#pragma unroll
      for (int js = 0; js < 64; js += 16) {
        bf16x8 kf0 = *(const bf16x8*)(skr + (js + lm) * 72 + lq * 8);
        bf16x8 kf1 = *(const bf16x8*)(skr + (js + lm) * 72 + 32 + lq * 8);
        f32x4 s = {0.f, 0.f, 0.f, 0.f};
        s = mfma16(qrf[0], kf0, s);
        s = mfma16(qrf[1], kf1, s);
#pragma unroll
        for (int r = 0; r < 4; ++r) {
          int jg = j0 + js + lm;
          int ig = i_base + lq * 4 + r;
          float p = (jg <= ig) ? __expf(s[r] * scale) : 0.0f;
          pl[w][(lq * 4 + r) * 72 + js + lm] = (bf16)p;
        }
      }
      __builtin_amdgcn_wave_barrier();
      bf16x8 pf0 = *(const bf16x8*)(pl[w] + lm * 72 + lq * 8);
      bf16x8 pf1 = *(const bf16x8*)(pl[w] + lm * 72 + 32 + lq * 8);
#pragma unroll
      for (int tt = 0; tt < 4; ++tt) {
        bf16x8 vf0 = *(const bf16x8*)(sv + (tt * 16 + lm) * 72 + lq * 8);
        bf16x8 vf1 = *(const bf16x8*)(sv + (tt * 16 + lm) * 72 + 32 + lq * 8);
        yacc[tt] = mfma16(pf0, vf0, mfma16(pf1, vf1, yacc[tt]));
      }
      __builtin_amdgcn_wave_barrier();
    }
  }
#undef FETCH_TILE
#pragma unroll
  for (int r = 0; r < 4; ++r) {
    float d = den[r];
    d += __shfl_xor(d, 1, 64);
    d += __shfl_xor(d, 2, 64);
    d += __shfl_xor(d, 4, 64);
    d += __shfl_xor(d, 8, 64);
    if (lm == 0) dp[(size_t)blk * 64 + w * 16 + lq * 4 + r] = d;
  }
  size_t yb = (size_t)blk * 4096;
#pragma unroll
  for (int tt = 0; tt < 4; ++tt)
#pragma unroll
    for (int r = 0; r < 4; ++r)
      yp[yb + (size_t)(w * 16 + lq * 4 + r) * 64 + tt * 16 + lm] = yacc[tt][r];
}

// ---------------- combine halves: y = (y0+y1)/(d0+d1) ----------------
__global__ __launch_bounds__(256) void combine_kernel(const float* __restrict__ yp,
                                                      const float* __restrict__ dp,
                                                      bf16* __restrict__ y) {
  int cb = blockIdx.x;  // 512
  int it = cb >> 5;
  int b = (cb >> 4) & 1;
  int h = cb & 15;
  int t = threadIdx.x;
  int row = t >> 2;
  int cg = (t & 3) * 16;
  size_t p0 = (size_t)(cb * 2) * 4096 + (size_t)row * 64 + cg;
  size_t p1 = p0 + 4096;
  float inv = 1.0f / (dp[(size_t)(cb * 2) * 64 + row] + dp[(size_t)(cb * 2 + 1) * 64 + row]);
  bf16x8 o0, o1;
#pragma unroll
  for (int c = 0; c < 8; ++c) o0[c] = (bf16)((yp[p0 + c] + yp[p1 + c]) * inv);
#pragma unroll
  for (int c = 0; c < 8; ++c) o1[c] = (bf16)((yp[p0 + 8 + c] + yp[p1 + 8 + c]) * inv);
  size_t ob = (size_t)(b * C_ + it * 64 + row) * D_ + h * DH_ + cg;
  *(bf16x8*)(y + ob) = o0;
  *(bf16x8*)(y + ob + 8) = o1;
}

extern "C" void kernel_launch(void* const* d_in, const int* in_sizes, int n_in,
                              void* d_out, int out_size, void* d_ws, size_t ws_size,
                              hipStream_t stream) {
  const float* x = (const float*)d_in[0];
  const float* rms_w = (const float*)d_in[1];
  const float* rms_b = (const float*)d_in[2];
  const float* Wqkv = (const float*)d_in[3];
  const float* Wout = (const float*)d_in[4];
  const float* bout = (const float*)d_in[5];
  const float* Wf = (const float*)d_in[6];
  const float* bfp = (const float*)d_in[7];
  const float* Ww = (const float*)d_in[8];
  const float* bw = (const float*)d_in[9];
  const float* Wv = (const float*)d_in[10];
  const float* bv = (const float*)d_in[11];
  const float* beta = (const float*)d_in[12];
  float* out = (float*)d_out;

  bf16* ws = (bf16*)d_ws;
  const size_t DD = (size_t)D_ * D_;
  const size_t MC = (size_t)B_ * C_;
  bf16* wb = ws;                       // 7DD: Wqkv(3), Wout, Wf, Ww, Wv
  bf16* x1 = ws + 7 * DD;
  bf16* qkv = ws + 9 * DD;
  bf16* vt = ws + 15 * DD;
  bf16* x2 = ws + 17 * DD;
  bf16* x3 = ws + 19 * DD;
  bf16* hbuf = ws + 21 * DD;
  float* yp = (float*)(ws + 24 * DD);  // 16 MB
  float* dp = yp + (size_t)1024 * 4096;
  bf16* y = (bf16*)d_out;  // bf16 y inside fp32 d_out; consumed before final write

  cvt_rms_kernel<<<7 * 1024 + MC, 256, 0, stream>>>(Wqkv, Wout, Wf, Ww, Wv, wb, x, rms_w,
                                                    rms_b, x1);
  gemm_qkv_kernel<<<dim3(3 * D_ / 64, MC / 128), 256, 0, stream>>>(x1, wb, qkv, vt);
  attn_kernel<<<B_ * H_ * 16 * 2, 256, 0, stream>>>(qkv, vt, yp, dp);
  combine_kernel<<<B_ * H_ * 16, 256, 0, stream>>>(yp, dp, y);
  gemm_lds<32, 64><<<dim3(D_ / 64, MC / 32), 256, 0, stream>>>(
      y, wb + 3 * DD, bout, x1, x2, MC, D_, D_);
  rmsnorm_bf16_kernel<<<MC, 256, 0, stream>>>(x2, rms_w, rms_b, x3);
  gemm_lds<32, 64><<<dim3(D_ / 64, MC / 32), 256, 0, stream>>>(
      x3, wb + 4 * DD, bfp, nullptr, hbuf, MC, D_, D_);
  gemm_ffn_kernel<<<dim3(D_ / 64, MC / 64), 256, 0, stream>>>(
      hbuf, wb + 5 * DD, wb + 6 * DD, bw, bv, x3, beta, out);
}

// Round 14
// 221.564 us; speedup vs baseline: 1.1322x; 1.0301x over previous
//
#include <hip/hip_runtime.h>
#include <math.h>

#define B_ 2
#define C_ 1024
#define D_ 1024
#define H_ 16
#define DH_ 64
#define EPSF 1e-8f
#define BK 32

typedef __bf16 bf16;
typedef __attribute__((ext_vector_type(4))) __bf16 bf16x4;
typedef __attribute__((ext_vector_type(8))) __bf16 bf16x8;
typedef __attribute__((ext_vector_type(4))) float f32x4;

__device__ inline f32x4 mfma16(bf16x8 a, bf16x8 b, f32x4 c) {
  return __builtin_amdgcn_mfma_f32_16x16x32_bf16(a, b, c, 0, 0, 0);
}

__device__ inline void async16(const bf16* g, bf16* l) {
  __builtin_amdgcn_global_load_lds((const __attribute__((address_space(1))) void*)g,
                                   (__attribute__((address_space(3))) void*)l, 16, 0, 0);
}

// theta for rope pair index i (reference uses (i-1)): 10000^(-2(i-1)/64)
__device__ inline float rope_theta(float i) {
  return exp2f(-13.287712379549449f * (2.0f * (i - 1.0f) * (1.0f / 64.0f)));
}

// ---------------- fused: weight cvt (segs 0..6) + RMSNorm fp32->bf16 (blocks 7168+) ----------------
__global__ __launch_bounds__(256) void cvt_rms_kernel(const float* __restrict__ wqkv,
                                                      const float* __restrict__ wout,
                                                      const float* __restrict__ wf,
                                                      const float* __restrict__ www,
                                                      const float* __restrict__ wv,
                                                      bf16* __restrict__ wdst,
                                                      const float* __restrict__ x,
                                                      const float* __restrict__ rw,
                                                      const float* __restrict__ rb,
                                                      bf16* __restrict__ xout) {
  __shared__ float red[4];
  int t = threadIdx.x;
  if (blockIdx.x < 7 * 1024) {
    int seg = blockIdx.x >> 10;
    int local = (blockIdx.x & 1023) * 1024 + t * 4;
    const float* src = seg < 3 ? wqkv + (size_t)seg * (D_ * D_)
                     : seg == 3 ? wout : seg == 4 ? wf : seg == 5 ? www : wv;
    float4 v = *(const float4*)(src + local);
    bf16x4 o;
    o[0] = (bf16)v.x; o[1] = (bf16)v.y; o[2] = (bf16)v.z; o[3] = (bf16)v.w;
    *(bf16x4*)(wdst + (size_t)seg * (D_ * D_) + local) = o;
    return;
  }
  int row = blockIdx.x - 7 * 1024;
  int c = row & (C_ - 1);
  float4 xv = *(const float4*)(x + (size_t)row * D_ + t * 4);
  float ss = xv.x * xv.x + xv.y * xv.y + xv.z * xv.z + xv.w * xv.w;
#pragma unroll
  for (int m = 1; m < 64; m <<= 1) ss += __shfl_xor(ss, m, 64);
  if ((t & 63) == 0) red[t >> 6] = ss;
  __syncthreads();
  float tot = red[0] + red[1] + red[2] + red[3];
  float inv = rsqrtf(tot * (1.0f / D_) + EPSF);
  float4 wv4 = *(const float4*)(rw + (size_t)c * D_ + t * 4);
  float4 bv4 = *(const float4*)(rb + (size_t)c * D_ + t * 4);
  bf16x4 ov;
  ov[0] = (bf16)(wv4.x * (xv.x * inv) + bv4.x);
  ov[1] = (bf16)(wv4.y * (xv.y * inv) + bv4.y);
  ov[2] = (bf16)(wv4.z * (xv.z * inv) + bv4.z);
  ov[3] = (bf16)(wv4.w * (xv.w * inv) + bv4.w);
  *(bf16x4*)(xout + (size_t)row * D_ + t * 4) = ov;
}

// ---------------- RMSNorm (bf16 in, bf16 out) ----------------
__global__ __launch_bounds__(256) void rmsnorm_bf16_kernel(const bf16* __restrict__ x,
                                                           const float* __restrict__ w,
                                                           const float* __restrict__ b,
                                                           bf16* __restrict__ out) {
  int row = blockIdx.x;
  int c = row & (C_ - 1);
  int t = threadIdx.x;
  bf16x4 xv = *(const bf16x4*)(x + (size_t)row * D_ + t * 4);
  float f0 = (float)xv[0], f1 = (float)xv[1], f2 = (float)xv[2], f3 = (float)xv[3];
  float ss = f0 * f0 + f1 * f1 + f2 * f2 + f3 * f3;
#pragma unroll
  for (int m = 1; m < 64; m <<= 1) ss += __shfl_xor(ss, m, 64);
  __shared__ float red[4];
  if ((t & 63) == 0) red[t >> 6] = ss;
  __syncthreads();
  float tot = red[0] + red[1] + red[2] + red[3];
  float inv = rsqrtf(tot * (1.0f / D_) + EPSF);
  float4 wv = *(const float4*)(w + (size_t)c * D_ + t * 4);
  float4 bv = *(const float4*)(b + (size_t)c * D_ + t * 4);
  bf16x4 ov;
  ov[0] = (bf16)(wv.x * (f0 * inv) + bv.x);
  ov[1] = (bf16)(wv.y * (f1 * inv) + bv.y);
  ov[2] = (bf16)(wv.z * (f2 * inv) + bv.z);
  ov[3] = (bf16)(wv.w * (f3 * inv) + bv.w);
  *(bf16x4*)(out + (size_t)row * D_ + t * 4) = ov;
}

// ---------------- generic GEMM (round-11 m97 structure, BK=32, <64,64>) ----------------
template <int BMt, int BNt>
__global__ __launch_bounds__(256) void gemm_lds(const bf16* __restrict__ A,
                                                const bf16* __restrict__ W,
                                                const float* __restrict__ bias,
                                                const bf16* __restrict__ R,
                                                bf16* __restrict__ Cout,
                                                int M, int N, int K) {
  constexpr int MT = BMt / 32;
  constexpr int NT = BNt / 32;
  __shared__ bf16 sa[BMt * BK];
  __shared__ bf16 sb[BNt * BK];
  int t = threadIdx.x, l = t & 63, w = t >> 6;
  int m0 = blockIdx.y * BMt;
  int n0 = blockIdx.x * BNt;
  int wm = (w >> 1) * (BMt / 2), wn = (w & 1) * (BNt / 2);
  int lm = l & 15, lq = l >> 4;
  f32x4 acc[MT][NT] = {};

  for (int k0 = 0; k0 < K; k0 += BK) {
    __syncthreads();
#pragma unroll
    for (int p = 0; p < BMt / 64; ++p) {
      int lin = p * 256 + t;
      async16(A + (size_t)(m0 + (lin >> 2)) * K + k0 + (lin & 3) * 8, sa + lin * 8);
    }
#pragma unroll
    for (int p = 0; p < BNt / 64; ++p) {
      int lin = p * 256 + t;
      async16(W + (size_t)(n0 + (lin >> 2)) * K + k0 + (lin & 3) * 8, sb + lin * 8);
    }
    __syncthreads();
    bf16x8 af[MT], bfr[NT];
#pragma unroll
    for (int mt = 0; mt < MT; ++mt)
      af[mt] = *(const bf16x8*)(sa + (wm + mt * 16 + lm) * BK + lq * 8);
#pragma unroll
    for (int nt = 0; nt < NT; ++nt)
      bfr[nt] = *(const bf16x8*)(sb + (wn + nt * 16 + lm) * BK + lq * 8);
#pragma unroll
    for (int mt = 0; mt < MT; ++mt)
#pragma unroll
      for (int nt = 0; nt < NT; ++nt)
        acc[mt][nt] = mfma16(af[mt], bfr[nt], acc[mt][nt]);
  }
#pragma unroll
  for (int mt = 0; mt < MT; ++mt)
#pragma unroll
    for (int nt = 0; nt < NT; ++nt) {
      int col = n0 + wn + nt * 16 + lm;
      float bb = bias ? bias[col] : 0.0f;
#pragma unroll
      for (int r = 0; r < 4; ++r) {
        int row = m0 + wm + mt * 16 + lq * 4 + r;
        float v = acc[mt][nt][r] + bb;
        if (R) v += (float)R[(size_t)row * N + col];
        Cout[(size_t)row * N + col] = (bf16)v;
      }
    }
}

// ---------------- QKV GEMM <128,64> BK=32 with fused V-transpose epilogue ----------------
__global__ __launch_bounds__(256) void gemm_qkv_kernel(const bf16* __restrict__ A,
                                                       const bf16* __restrict__ W,
                                                       bf16* __restrict__ qkv,
                                                       bf16* __restrict__ vt) {
  constexpr int BMt = 128, BNt = 64, MT = 4, NT = 2;
  const int N = 3 * D_, K = D_;
  __shared__ bf16 sa[BMt * BK];
  __shared__ bf16 sb[BNt * BK];
  __shared__ bf16 tv[64 * 136];  // V transpose tile [dh][m]
  int t = threadIdx.x, l = t & 63, w = t >> 6;
  int m0 = blockIdx.y * BMt;
  int n0 = blockIdx.x * BNt;
  int wm = (w >> 1) * 64, wn = (w & 1) * 32;
  int lm = l & 15, lq = l >> 4;
  f32x4 acc[MT][NT] = {};

  for (int k0 = 0; k0 < K; k0 += BK) {
    __syncthreads();
#pragma unroll
    for (int p = 0; p < 2; ++p) {
      int lin = p * 256 + t;
      async16(A + (size_t)(m0 + (lin >> 2)) * K + k0 + (lin & 3) * 8, sa + lin * 8);
    }
    async16(W + (size_t)(n0 + (t >> 2)) * K + k0 + (t & 3) * 8, sb + t * 8);
    __syncthreads();
    bf16x8 af[MT], bfr[NT];
#pragma unroll
    for (int mt = 0; mt < MT; ++mt)
      af[mt] = *(const bf16x8*)(sa + (wm + mt * 16 + lm) * BK + lq * 8);
#pragma unroll
    for (int nt = 0; nt < NT; ++nt)
      bfr[nt] = *(const bf16x8*)(sb + (wn + nt * 16 + lm) * BK + lq * 8);
#pragma unroll
    for (int mt = 0; mt < MT; ++mt)
#pragma unroll
      for (int nt = 0; nt < NT; ++nt)
        acc[mt][nt] = mfma16(af[mt], bfr[nt], acc[mt][nt]);
  }
  if (n0 < 2 * D_) {
#pragma unroll
    for (int mt = 0; mt < MT; ++mt)
#pragma unroll
      for (int nt = 0; nt < NT; ++nt) {
        int col = n0 + wn + nt * 16 + lm;
#pragma unroll
        for (int r = 0; r < 4; ++r) {
          int row = m0 + wm + mt * 16 + lq * 4 + r;
          qkv[(size_t)row * N + col] = (bf16)acc[mt][nt][r];
        }
      }
  } else {
#pragma unroll
    for (int mt = 0; mt < MT; ++mt)
#pragma unroll
      for (int nt = 0; nt < NT; ++nt) {
        int dh = wn + nt * 16 + lm;
#pragma unroll
        for (int r = 0; r < 4; ++r)
          tv[dh * 136 + wm + mt * 16 + lq * 4 + r] = (bf16)acc[mt][nt][r];
      }
    __syncthreads();
    int h = (n0 - 2 * D_) >> 6;
    int bb = m0 >> 10;
    int mloc = m0 & 1023;
    size_t vbase = (size_t)((bb * H_ + h) * DH_) * C_;
#pragma unroll
    for (int p = 0; p < 4; ++p) {
      int lin = p * 256 + t;
      int dh = lin >> 4;
      int mm = (lin & 15) * 8;
      *(int4*)(vt + vbase + (size_t)dh * C_ + mloc + mm) = *(int4*)(tv + dh * 136 + mm);
    }
  }
}

// ---------------- Fused FFN tail (BK=32) ----------------
__global__ __launch_bounds__(256) void gemm_ffn_kernel(const bf16* __restrict__ A,
                                                       const bf16* __restrict__ Ww,
                                                       const bf16* __restrict__ Wv,
                                                       const float* __restrict__ bw,
                                                       const float* __restrict__ bv,
                                                       const bf16* __restrict__ x3,
                                                       const float* __restrict__ beta_p,
                                                       float* __restrict__ out) {
  __shared__ bf16 sa[64 * BK];
  __shared__ bf16 sb1[64 * BK];
  __shared__ bf16 sb2[64 * BK];
  int t = threadIdx.x, l = t & 63, w = t >> 6;
  int m0 = blockIdx.y * 64, n0 = blockIdx.x * 64;
  int wm = (w >> 1) * 32, wn = (w & 1) * 32;
  int lm = l & 15, lq = l >> 4;
  float beta = beta_p[0];
  f32x4 acc1[2][2] = {}, acc2[2][2] = {};

  for (int k0 = 0; k0 < D_; k0 += BK) {
    __syncthreads();
    async16(A + (size_t)(m0 + (t >> 2)) * D_ + k0 + (t & 3) * 8, sa + t * 8);
    async16(Ww + (size_t)(n0 + (t >> 2)) * D_ + k0 + (t & 3) * 8, sb1 + t * 8);
    async16(Wv + (size_t)(n0 + (t >> 2)) * D_ + k0 + (t & 3) * 8, sb2 + t * 8);
    __syncthreads();
    bf16x8 af[2], b1f[2], b2f[2];
#pragma unroll
    for (int mt = 0; mt < 2; ++mt)
      af[mt] = *(const bf16x8*)(sa + (wm + mt * 16 + lm) * BK + lq * 8);
#pragma unroll
    for (int nt = 0; nt < 2; ++nt) {
      b1f[nt] = *(const bf16x8*)(sb1 + (wn + nt * 16 + lm) * BK + lq * 8);
      b2f[nt] = *(const bf16x8*)(sb2 + (wn + nt * 16 + lm) * BK + lq * 8);
    }
#pragma unroll
    for (int mt = 0; mt < 2; ++mt)
#pragma unroll
      for (int nt = 0; nt < 2; ++nt) {
        acc1[mt][nt] = mfma16(af[mt], b1f[nt], acc1[mt][nt]);
        acc2[mt][nt] = mfma16(af[mt], b2f[nt], acc2[mt][nt]);
      }
  }
#pragma unroll
  for (int mt = 0; mt < 2; ++mt)
#pragma unroll
    for (int nt = 0; nt < 2; ++nt) {
      int col = n0 + wn + nt * 16 + lm;
      float bbw = bw[col], bbv = bv[col];
#pragma unroll
      for (int r = 0; r < 4; ++r) {
        int row = m0 + wm + mt * 16 + lq * 4 + r;
        float z = acc1[mt][nt][r] + bbw;
        float g = acc2[mt][nt][r] + bbv;
        float sw = z / (1.0f + __expf(-beta * z));
        out[(size_t)row * D_ + col] = (float)x3[(size_t)row * D_ + col] + sw * g;
      }
    }
}

// ---------------- Fused attention v5: UN-SPLIT (full j-loop), direct y write ----------------
// blk = it*32 + b*16 + h ; 512 blocks. i-rows [it*64,+64), j in [0,1024).
__global__ __launch_bounds__(256) void attn_kernel(const bf16* __restrict__ qkv,
                                                   const bf16* __restrict__ vt,
                                                   bf16* __restrict__ y) {
  __shared__ bf16 sk[64 * 72];
  __shared__ bf16 skr[64 * 72];
  __shared__ bf16 sv[64 * 72];
  __shared__ bf16 pl[4][16 * 72];
  int t = threadIdx.x, l = t & 63, w = t >> 6;
  int blk = blockIdx.x;  // 512
  int it = blk >> 5;     // high bits: CU pairs get it=(k,k+8) -> balanced causal work
  int r5 = blk & 31;
  int b = r5 >> 4;
  int h = r5 & 15;
  int i_base = it * 64 + w * 16;
  int lm = l & 15, lq = l >> 4;
  const float scale = 0.125f;

  size_t hq = (size_t)h * DH_;
  size_t qrow = (size_t)(b * C_ + i_base + lm) * (3 * D_) + hq;
  bf16x8 qp[2], qrf[2];
  float cq = (float)(i_base + lm);
#pragma unroll
  for (int kk = 0; kk < 2; ++kk) {
    qp[kk] = *(const bf16x8*)(qkv + qrow + kk * 32 + lq * 8);
#pragma unroll
    for (int j = 0; j < 4; ++j) {
      float ip = (float)(kk * 16 + lq * 4 + j);
      float ang = cq * rope_theta(ip);
      float sv_, cv_;
      __sincosf(ang, &sv_, &cv_);
      float qe = (float)qp[kk][2 * j], qo = (float)qp[kk][2 * j + 1];
      qrf[kk][2 * j] = (bf16)(qe * cv_ + qo * sv_);
      qrf[kk][2 * j + 1] = (bf16)(qo * cv_ - qe * sv_);
    }
  }

  float den[4] = {0.f, 0.f, 0.f, 0.f};
  f32x4 yacc[4] = {};
  int i_max = i_base + 15;
  size_t kbase = (size_t)(b * C_) * (3 * D_) + D_ + hq;
  size_t vtbase = (size_t)((b * H_ + h) * DH_) * C_;
  int sr = t >> 3;
  int sc = (t & 7) * 8;
  float th0 = rope_theta((float)((sc >> 1) + 0));
  float th1 = rope_theta((float)((sc >> 1) + 1));
  float th2 = rope_theta((float)((sc >> 1) + 2));
  float th3 = rope_theta((float)((sc >> 1) + 3));

  // K-rope rotation state (recurrence; NAMED SCALARS - round-6 spill lesson).
  float cA0, sA0, cA1, sA1, cA2, sA2, cA3, sA3;
  float cB0, sB0, cB1, sB1, cB2, sB2, cB3, sB3;
  float C0, S0, C1, S1, C2, S2, C3, S3;
#define INITP(P)                  \
  {                               \
    float a;                      \
    a = (float)(sr)*th##P;        \
    __sincosf(a, &sA##P, &cA##P); \
    a = (float)(32 + sr) * th##P; \
    __sincosf(a, &sB##P, &cB##P); \
    a = 64.0f * th##P;            \
    __sincosf(a, &S##P, &C##P);   \
  }
  INITP(0) INITP(1) INITP(2) INITP(3)
#undef INITP

  int4 pk0, pk1, pv0, pv1;
#define FETCH_TILE(J0)                                                          \
  pk0 = *(const int4*)(qkv + kbase + (size_t)((J0) + sr) * (3 * D_) + sc);      \
  pk1 = *(const int4*)(qkv + kbase + (size_t)((J0) + 32 + sr) * (3 * D_) + sc); \
  pv0 = *(const int4*)(vt + vtbase + (size_t)sr * C_ + (J0) + sc);              \
  pv1 = *(const int4*)(vt + vtbase + (size_t)(32 + sr) * C_ + (J0) + sc);

  FETCH_TILE(0)

  for (int j0 = 0; j0 < C_; j0 += 64) {
    __syncthreads();
    *(int4*)(sk + sr * 72 + sc) = pk0;
    *(int4*)(sk + (32 + sr) * 72 + sc) = pk1;
    *(int4*)(sv + sr * 72 + sc) = pv0;
    *(int4*)(sv + (32 + sr) * 72 + sc) = pv1;
    {
      bf16x8 k0 = *(bf16x8*)&pk0, k1 = *(bf16x8*)&pk1;
      bf16x8 r0, r1;
#define ROT2(KV, RV, CC, SS, J)                           \
  {                                                       \
    float e = (float)KV[2 * J], o = (float)KV[2 * J + 1]; \
    RV[2 * J] = (bf16)(e * CC + o * SS);                  \
    RV[2 * J + 1] = (bf16)(o * CC - e * SS);              \
  }
      ROT2(k0, r0, cA0, sA0, 0) ROT2(k0, r0, cA1, sA1, 1)
      ROT2(k0, r0, cA2, sA2, 2) ROT2(k0, r0, cA3, sA3, 3)
      ROT2(k1, r1, cB0, sB0, 0) ROT2(k1, r1, cB1, sB1, 1)
      ROT2(k1, r1, cB2, sB2, 2) ROT2(k1, r1, cB3, sB3, 3)
#undef ROT2
#define STEP(CX, SX, P)               \
  {                                   \
    float nc = CX * C##P - SX * S##P; \
    SX = SX * C##P + CX * S##P;       \
    CX = nc;                          \
  }
      STEP(cA0, sA0, 0) STEP(cA1, sA1, 1) STEP(cA2, sA2, 2) STEP(cA3, sA3, 3)
      STEP(cB0, sB0, 0) STEP(cB1, sB1, 1) STEP(cB2, sB2, 2) STEP(cB3, sB3, 3)
#undef STEP
      *(int4*)(skr + sr * 72 + sc) = *(int4*)&r0;
      *(int4*)(skr + (32 + sr) * 72 + sc) = *(int4*)&r1;
    }
    __syncthreads();
    if (j0 + 64 < C_) {
      FETCH_TILE(j0 + 64)
    }
    // denominator: unrotated q.k over all j
#pragma unroll
    for (int js = 0; js < 64; js += 16) {
      bf16x8 kf0 = *(const bf16x8*)(sk + (js + lm) * 72 + lq * 8);
      bf16x8 kf1 = *(const bf16x8*)(sk + (js + lm) * 72 + 32 + lq * 8);
      f32x4 s = {0.f, 0.f, 0.f, 0.f};
      s = mfma16(qp[0], kf0, s);
      s = mfma16(qp[1], kf1, s);
#pragma unroll
      for (int r = 0; r < 4; ++r) den[r] += __expf(s[r] * scale);
    }
    // numerator + PV: causal tiles only (wave-uniform guard)
    if (j0 <= i_max) {
#pragma unroll
      for (int js = 0; js < 64; js += 16) {
        bf16x8 kf0 = *(const bf16x8*)(skr + (js + lm) * 72 + lq * 8);
        bf16x8 kf1 = *(const bf16x8*)(skr + (js + lm) * 72 + 32 + lq * 8);
        f32x4 s = {0.f, 0.f, 0.f, 0.f};
        s = mfma16(qrf[0], kf0, s);
        s = mfma16(qrf[1], kf1, s);
#pragma unroll
        for (int r = 0; r < 4; ++r) {
          int jg = j0 + js + lm;
          int ig = i_base + lq * 4 + r;
          float p = (jg <= ig) ? __expf(s[r] * scale) : 0.0f;
          pl[w][(lq * 4 + r) * 72 + js + lm] = (bf16)p;
        }
      }
      __builtin_amdgcn_wave_barrier();
      bf16x8 pf0 = *(const bf16x8*)(pl[w] + lm * 72 + lq * 8);
      bf16x8 pf1 = *(const bf16x8*)(pl[w] + lm * 72 + 32 + lq * 8);
#pragma unroll
      for (int tt = 0; tt < 4; ++tt) {
        bf16x8 vf0 = *(const bf16x8*)(sv + (tt * 16 + lm) * 72 + lq * 8);
        bf16x8 vf1 = *(const bf16x8*)(sv + (tt * 16 + lm) * 72 + 32 + lq * 8);
        yacc[tt] = mfma16(pf0, vf0, mfma16(pf1, vf1, yacc[tt]));
      }
      __builtin_amdgcn_wave_barrier();
    }
  }
#undef FETCH_TILE
  // normalize in-register and write y directly (no combine pass)
  float inv[4];
#pragma unroll
  for (int r = 0; r < 4; ++r) {
    float d = den[r];
    d += __shfl_xor(d, 1, 64);
    d += __shfl_xor(d, 2, 64);
    d += __shfl_xor(d, 4, 64);
    d += __shfl_xor(d, 8, 64);
    inv[r] = 1.0f / d;
  }
#pragma unroll
  for (int tt = 0; tt < 4; ++tt)
#pragma unroll
    for (int r = 0; r < 4; ++r) {
      int ig = i_base + lq * 4 + r;
      y[(size_t)(b * C_ + ig) * D_ + hq + tt * 16 + lm] = (bf16)(yacc[tt][r] * inv[r]);
    }
}

extern "C" void kernel_launch(void* const* d_in, const int* in_sizes, int n_in,
                              void* d_out, int out_size, void* d_ws, size_t ws_size,
                              hipStream_t stream) {
  const float* x = (const float*)d_in[0];
  const float* rms_w = (const float*)d_in[1];
  const float* rms_b = (const float*)d_in[2];
  const float* Wqkv = (const float*)d_in[3];
  const float* Wout = (const float*)d_in[4];
  const float* bout = (const float*)d_in[5];
  const float* Wf = (const float*)d_in[6];
  const float* bfp = (const float*)d_in[7];
  const float* Ww = (const float*)d_in[8];
  const float* bw = (const float*)d_in[9];
  const float* Wv = (const float*)d_in[10];
  const float* bv = (const float*)d_in[11];
  const float* beta = (const float*)d_in[12];
  float* out = (float*)d_out;

  bf16* ws = (bf16*)d_ws;
  const size_t DD = (size_t)D_ * D_;
  const size_t MC = (size_t)B_ * C_;
  bf16* wb = ws;            // 7DD: Wqkv(3), Wout, Wf, Ww, Wv
  bf16* x1 = ws + 7 * DD;
  bf16* qkv = ws + 9 * DD;
  bf16* vt = ws + 15 * DD;
  bf16* x2 = ws + 17 * DD;
  bf16* x3 = ws + 19 * DD;
  bf16* hbuf = ws + 21 * DD;
  bf16* y = (bf16*)d_out;   // bf16 y inside fp32 d_out; consumed before final write

  cvt_rms_kernel<<<7 * 1024 + MC, 256, 0, stream>>>(Wqkv, Wout, Wf, Ww, Wv, wb, x, rms_w,
                                                    rms_b, x1);
  gemm_qkv_kernel<<<dim3(3 * D_ / 64, MC / 128), 256, 0, stream>>>(x1, wb, qkv, vt);
  attn_kernel<<<B_ * H_ * 16, 256, 0, stream>>>(qkv, vt, y);
  gemm_lds<64, 64><<<dim3(D_ / 64, MC / 64), 256, 0, stream>>>(
      y, wb + 3 * DD, bout, x1, x2, MC, D_, D_);
  rmsnorm_bf16_kernel<<<MC, 256, 0, stream>>>(x2, rms_w, rms_b, x3);
  gemm_lds<64, 64><<<dim3(D_ / 64, MC / 64), 256, 0, stream>>>(
      x3, wb + 4 * DD, bfp, nullptr, hbuf, MC, D_, D_);
  gemm_ffn_kernel<<<dim3(D_ / 64, MC / 64), 256, 0, stream>>>(
      hbuf, wb + 5 * DD, wb + 6 * DD, bw, bv, x3, beta, out);
}